// Round 2
// baseline (915.199 us; speedup 1.0000x reference)
//
#include <hip/hip_runtime.h>

#define T_STEPS 336
#define NWG_LAUNCH 256   // full machine, 1 WG/CU; only bid&7==0 persist => 32 WGs,
                         // all on XCD 0 under the measured round-robin dispatch.

typedef unsigned long long u64;

// Device-global scratch. First launch: .bss zeros = tag0|h0=0 (valid t=0 state).
// Later launches: each slot's OWNING WG re-tags it for t=0 (both parities, both
// transports) at startup; stale terminal tags (336/335) never match startup
// targets (0/1), and within a launch slot tags are monotone 0..336.
__device__ float g_h[337 * 512];      // h_1..h_336 (head reads t>=81)
__device__ float g_blw[256 * 512];    // sampled BayesianLinear weight
__device__ u64   g_fast[2][512];      // parity bufs: XCD-L2 path (sc0)
__device__ u64   g_slow[2][512];      // parity bufs: MALL path (agent) — proven baseline transport

__device__ __forceinline__ float softplus_f(float x) {
  return (x > 20.f) ? x : log1pf(__expf(x));
}
__device__ __forceinline__ float sigmoid_f(float x) {
  return 1.f / (1.f + __expf(-x));
}
__device__ __forceinline__ float tanh_f(float x) {
  x = fminf(fmaxf(x, -15.f), 15.f);
  float e = __expf(-2.f * x);
  return (1.f - e) / (1.f + e);
}

// sc0 = L1-bypass, L2-coherent: CU-to-CU visibility through the shared
// per-XCD L2 (~120-200cy) instead of agent/MALL (~500-900cy).
__device__ __forceinline__ u64 ld_l2(const u64* p) {
  u64 v;
  asm volatile("global_load_dwordx2 %0, %1, off sc0\n\t"
               "s_waitcnt vmcnt(0)"
               : "=&v"(v) : "v"(p) : "memory");
  return v;
}
__device__ __forceinline__ void st_l2(u64* p, u64 v) {
  asm volatile("global_store_dwordx2 %0, %1, off sc0"
               :: "v"(p), "v"(v) : "memory");
}

// ---------------- persistent LSTM recurrence ----------------
// 32 active WGs x 512 threads. DUAL-PUBLISH transport (deadlock-free by
// construction — both publishes happen in the producer's step-t tail, exactly
// the proven baseline structure; round-1's post-barrier mirror republish
// created a barrier<->publish cycle and deadlocked into the anti-hang path):
//   producer lanes write h as (tag<<32|bits) to g_fast via sc0 (fast when
//   consumer shares the XCD's L2) AND to g_slow via relaxed agent atomics
//   (the baseline MALL transport, correct under ANY placement).
// Consumers poll fast every iteration, probe slow every 8th. If the
// round-robin placement hypothesis holds, pickup is an L2 round trip; if it
// doesn't, the kernel degrades to ~baseline speed with correct results.
// WG r owns h-indices [16r,16r+16). Thread (seg=tid>>6, cl=tid&63):
// col=(cl>>4)*512+16r+(cl&15), rows [64seg,64seg+64), 64 sampled Whh weights
// in registers (FULL unroll or w[] demotes to scratch). Wave seg polls exactly
// the 64 h-slots its dot consumes -> no poll->dot barrier; part[] parity-
// double-buffered -> single __syncthreads per step. Parity reuse is safe:
// all-to-all consumption each step means tag t is consumed by every WG before
// any WG can publish tag t+2 into the same slot.
__global__ __launch_bounds__(512) void lstm_kernel(
    const float* __restrict__ x, const float* __restrict__ drop_x,
    const float* __restrict__ wih_mu, const float* __restrict__ wih_rho, const float* __restrict__ eps_wih,
    const float* __restrict__ b_mu, const float* __restrict__ b_rho, const float* __restrict__ eps_b,
    const float* __restrict__ whh_mu, const float* __restrict__ whh_rho, const float* __restrict__ eps_whh,
    const float* __restrict__ blw_mu, const float* __restrict__ blw_rho, const float* __restrict__ eps_blw)
{
  const int bid = blockIdx.x;
  if (bid & 7) return;              // keep only XCD-0 residents (round-robin)
  const int r = bid >> 3;           // 0..31: WG role
  const int tid = threadIdx.x;      // 0..511
  const int cl = tid & 63;
  const int seg = tid >> 6;         // 0..7
  const int gate = cl >> 4, kl = cl & 15;
  const int col = gate * 512 + r * 16 + kl;
  const int row0 = seg * 64;

  // FIRST: re-tag my own 16 slots for t=0 (both parities, both transports).
  // Owners-only -> no cross-WG write races; consumers' t=0 polls wait for
  // these (or hit first-launch .bss zeros, which are the valid t=0 state).
  if (tid < 16) {
    const int idx = r * 16 + tid;
    st_l2(&g_fast[0][idx], 0ULL);
    st_l2(&g_fast[1][idx], 0ULL);
    __hip_atomic_store(&g_slow[0][idx], 0ULL, __ATOMIC_RELAXED, __HIP_MEMORY_SCOPE_AGENT);
    __hip_atomic_store(&g_slow[1][idx], 0ULL, __ATOMIC_RELAXED, __HIP_MEMORY_SCOPE_AGENT);
  }

  __shared__ float xd[336 * 16];    // x*drop_x for batch 255
  __shared__ float hs[512];         // fp32 h copy (wave-local segments)
  __shared__ float part[2][8][64];  // parity-double-buffered partials

  // One-time: sample BLW (consumed by head after this kernel completes).
  {
    const int e0 = (r * 512 + tid) * 8;
    #pragma unroll
    for (int q = 0; q < 8; ++q) {
      const int e = e0 + q;
      g_blw[e] = blw_mu[e] + softplus_f(blw_rho[e]) * eps_blw[e];
    }
  }

  for (int e = tid; e < 5376; e += 512) {
    const int src = 255 * 5376 + e;   // batch-255 slice is contiguous
    xd[e] = x[src] * drop_x[src];
  }

  // 64 sampled Whh weights into registers.
  float w[64];
  #pragma unroll
  for (int j = 0; j < 64; ++j) {
    const int idx = (row0 + j) * 2048 + col;
    w[j] = whh_mu[idx] + softplus_f(whh_rho[idx]) * eps_whh[idx];
  }

  // Wave 0: Wih column + bias for on-the-fly xg.
  float wih[16];
  float bias = 0.f;
  if (tid < 64) {
    bias = b_mu[col] + softplus_f(b_rho[col]) * eps_b[col];
    #pragma unroll
    for (int i = 0; i < 16; ++i) {
      const int idx = i * 2048 + col;
      wih[i] = wih_mu[idx] + softplus_f(wih_rho[idx]) * eps_wih[idx];
    }
  }
  __syncthreads();                  // xd staged

  auto xg_at = [&](int t) -> float {
    const float4* xr = (const float4*)(xd + t * 16);
    float4 x0 = xr[0], x1 = xr[1], x2 = xr[2], x3 = xr[3];
    float s0 = fmaf(x0.x, wih[0], bias);
    s0 = fmaf(x0.y, wih[1], s0); s0 = fmaf(x0.z, wih[2], s0); s0 = fmaf(x0.w, wih[3], s0);
    float s1 = x1.x * wih[4];
    s1 = fmaf(x1.y, wih[5], s1); s1 = fmaf(x1.z, wih[6], s1); s1 = fmaf(x1.w, wih[7], s1);
    float s2 = x2.x * wih[8];
    s2 = fmaf(x2.y, wih[9], s2); s2 = fmaf(x2.z, wih[10], s2); s2 = fmaf(x2.w, wih[11], s2);
    float s3 = x3.x * wih[12];
    s3 = fmaf(x3.y, wih[13], s3); s3 = fmaf(x3.z, wih[14], s3); s3 = fmaf(x3.w, wih[15], s3);
    return (s0 + s1) + (s2 + s3);
  };

  float c = 0.f;                    // cell state (wave-0 lanes 0..15)
  float xgv = (tid < 64) ? xg_at(0) : 0.f;

  for (int t = 0; t < T_STEPS; ++t) {
    const int p = t & 1;

    // Poll my slot: fast path through the shared L2; every 8th iteration
    // probe the MALL (agent) slot so any placement still makes progress.
    {
      const u64* fsl = &g_fast[p][tid];
      u64 v;
      unsigned it = 0;
      for (;;) {
        v = ld_l2(fsl);
        if ((unsigned)(v >> 32) == (unsigned)t) break;
        if ((++it & 7u) == 0u) {
          v = __hip_atomic_load(&g_slow[p][tid], __ATOMIC_RELAXED,
                                __HIP_MEMORY_SCOPE_AGENT);
          if ((unsigned)(v >> 32) == (unsigned)t) break;
        }
        if (it > (1u << 22)) break;   // anti-hang insurance (never fires: slow path is proven)
      }
      hs[tid] = __uint_as_float((unsigned)v);
    }
    // No barrier: wave seg's dot reads hs[row0..row0+64) = its own lanes' data.

    float a0 = 0.f, a1 = 0.f, a2 = 0.f, a3 = 0.f;
    const float4* hv = (const float4*)(hs + row0);
    #pragma unroll
    for (int jj = 0; jj < 16; ++jj) {
      float4 h4 = hv[jj];
      a0 = fmaf(h4.x, w[4 * jj],     a0);
      a1 = fmaf(h4.y, w[4 * jj + 1], a1);
      a2 = fmaf(h4.z, w[4 * jj + 2], a2);
      a3 = fmaf(h4.w, w[4 * jj + 3], a3);
    }
    part[p][seg][cl] = (a0 + a1) + (a2 + a3);
    __syncthreads();   // single rendezvous per step (skew-safe via parity bufs)

    if (tid < 64) {
      float g = xgv
              + ((part[p][0][tid] + part[p][1][tid]) + (part[p][2][tid] + part[p][3][tid]))
              + ((part[p][4][tid] + part[p][5][tid]) + (part[p][6][tid] + part[p][7][tid]));
      // Parallel activation on all 64 lanes (one exp chain each):
      // gates i,f,o -> sigmoid; gate g -> tanh = 2*sigmoid(2x)-1 (clamped).
      const bool is_g = (gate == 2);
      float xin = is_g ? 2.f * fminf(fmaxf(g, -15.f), 15.f) : g;
      float s = sigmoid_f(xin);
      float act = is_g ? 2.f * s - 1.f : s;
      float vi = __shfl(act, kl);
      float vf = __shfl(act, kl + 16);
      float vg = __shfl(act, kl + 32);
      float vo = __shfl(act, kl + 48);
      if (tid < 16) {
        c = vf * c + vi * vg;
        float h = vo * tanh_f(c);
        const int idx = r * 16 + tid;
        u64 pv = (((u64)(unsigned)(t + 1)) << 32) | (u64)__float_as_uint(h);
        st_l2(&g_fast[(t + 1) & 1][idx], pv);          // fast publish (XCD L2)
        __hip_atomic_store(&g_slow[(t + 1) & 1][idx], pv,
                           __ATOMIC_RELAXED, __HIP_MEMORY_SCOPE_AGENT);  // proven MALL publish
        g_h[(t + 1) * 512 + idx] = h;                  // for head (kernel-end flush)
      }
      if (t + 1 < T_STEPS) xgv = xg_at(t + 1);         // off critical path
    }
  }
}

// ---------------- head ----------------
// block j: last[j] = g_h[81+j]  (reshape(T,B,H)[-1] => h_{t=80+j} of batch 255)
// y[l] = relu(last*drop_h[j] . BLW[l] + BLb[l]) * drop_l[j,l]; out = y @ lin_w^T.
// BLb sampled inline per block (256 redundant softplus -- free).
__global__ __launch_bounds__(256) void head_kernel(
    const float* __restrict__ drop_h, const float* __restrict__ drop_l,
    const float* __restrict__ blb_mu, const float* __restrict__ blb_rho,
    const float* __restrict__ eps_blb,
    const float* __restrict__ lin_w, float* __restrict__ out)
{
  const int j = blockIdx.x, tid = threadIdx.x;
  __shared__ float hd[512];
  __shared__ float y[256];

  for (int k = tid; k < 512; k += 256)
    hd[k] = g_h[(81 + j) * 512 + k] * drop_h[j * 512 + k];
  __syncthreads();

  {
    const int l = tid;
    float acc = blb_mu[l] + softplus_f(blb_rho[l]) * eps_blb[l];
    const float* wrow = g_blw + l * 512;
    #pragma unroll 8
    for (int k = 0; k < 512; ++k) acc = fmaf(hd[k], wrow[k], acc);
    acc = fmaxf(acc, 0.f);
    y[l] = acc * drop_l[j * 256 + l];
  }
  __syncthreads();

  if (tid < 10) {
    float acc = 0.f;
    const float* lrow = lin_w + tid * 256;
    #pragma unroll 8
    for (int l = 0; l < 256; ++l) acc = fmaf(y[l], lrow[l], acc);
    out[j * 10 + tid] = acc;
  }
}

// ---------------- launch (2 dispatches) ----------------
extern "C" void kernel_launch(void* const* d_in, const int* in_sizes, int n_in,
                              void* d_out, int out_size, void* d_ws, size_t ws_size,
                              hipStream_t stream) {
  const float* x        = (const float*)d_in[0];
  const float* drop_x   = (const float*)d_in[1];
  const float* drop_h   = (const float*)d_in[2];
  const float* drop_l   = (const float*)d_in[3];
  const float* wih_mu   = (const float*)d_in[4];
  const float* wih_rho  = (const float*)d_in[5];
  const float* eps_wih  = (const float*)d_in[6];
  const float* whh_mu   = (const float*)d_in[7];
  const float* whh_rho  = (const float*)d_in[8];
  const float* eps_whh  = (const float*)d_in[9];
  const float* b_mu     = (const float*)d_in[10];
  const float* b_rho    = (const float*)d_in[11];
  const float* eps_b    = (const float*)d_in[12];
  const float* blw_mu   = (const float*)d_in[13];
  const float* blw_rho  = (const float*)d_in[14];
  const float* eps_blw  = (const float*)d_in[15];
  const float* blb_mu   = (const float*)d_in[16];
  const float* blb_rho  = (const float*)d_in[17];
  const float* eps_blb  = (const float*)d_in[18];
  const float* lin_w    = (const float*)d_in[19];

  lstm_kernel<<<NWG_LAUNCH, 512, 0, stream>>>(x, drop_x,
                                              wih_mu, wih_rho, eps_wih,
                                              b_mu, b_rho, eps_b,
                                              whh_mu, whh_rho, eps_whh,
                                              blw_mu, blw_rho, eps_blw);

  head_kernel<<<256, 256, 0, stream>>>(drop_h, drop_l,
                                       blb_mu, blb_rho, eps_blb,
                                       lin_w, (float*)d_out);
}